// Round 12
// baseline (108.066 us; speedup 1.0000x reference)
//
#include <hip/hip_runtime.h>
#include <stdint.h>

#define BQ 4
#define CC 3
#define MM 4096
#define NN 8192
#define KK 16
#define NP_OFF (BQ*CC*MM*KK)    // coords first, then indices
#define BLOCK 512
#define RPW 8                    // rows per wave (R10: 16 -> AGPR shuttle; keep 8)
#define GROUPS 2                 // row groups per block
#define ROWS 16                  // rows per block
#define CHUNK 1024               // points per LDS buffer (16 KB of float4)
#define NCH 8                    // total chunks
#define SCH 4                    // pass-1 sample chunks (half the points)
#define QST 4                    // steps per quarter-wave per chunk
#define EPSD 1e-4f               // dotf-space slack (folded vs reference ~1e-6)
#define CANDMAX 128

__device__ __forceinline__ float rfl(float x) {
    return __uint_as_float((unsigned)__builtin_amdgcn_readfirstlane((int)__float_as_uint(x)));
}
// order-preserving float<->uint maps (monotone increasing)
__device__ __forceinline__ unsigned mapf(float f) {
    unsigned u = __float_as_uint(f);
    return (u & 0x80000000u) ? ~u : (u | 0x80000000u);
}
__device__ __forceinline__ float unmapf(unsigned u) {
    unsigned b = (u & 0x80000000u) ? (u & 0x7fffffffu) : ~u;
    return __uint_as_float(b);
}

// ---- prep: AoS {x,y,z,-0.5*p2} table in d_ws (reference rounding for p2;
//      x,y,z pass through unchanged; -0.5*p2 is exact scaling) ----
__global__ __launch_bounds__(256) void prep_kernel(
    const float* __restrict__ points, float4* __restrict__ ws4)
{
    int i = blockIdx.x * 256 + threadIdx.x;      // 0..32767
    int b = i >> 13, n = i & (NN - 1);
    const float* pb = points + b * (CC * NN);
    float px = pb[n], py = pb[NN + n], pz = pb[2*NN + n];
    float p2 = __fadd_rn(__fadd_rn(__fmul_rn(px,px), __fmul_rn(py,py)),
                         __fmul_rn(pz,pz));
    ws4[i] = make_float4(px, py, pz, -0.5f * p2);
}

__global__ __launch_bounds__(BLOCK, 8) void knn_kernel(
    const float* __restrict__ query,
    const float4* __restrict__ ws4,
    float* __restrict__ out)
{
    __shared__ float4 pts[2][CHUNK];     // 32 KB dbuf {x,y,z,-p2/2}
    __shared__ unsigned aux[ROWS][64];   // 4 KB: slot-max, then ushort cand[128]
    __shared__ unsigned scnt[ROWS];
    __shared__ unsigned rcbits[ROWS];

    const int tid  = threadIdx.x;
    const int lane = tid & 63;
    const int wv   = tid >> 6;             // 0..7
    const int g    = wv >> 2;              // row group 0..1
    const int qt   = wv & 3;               // point-quarter 0..3
    const int bid  = blockIdx.x;           // 0..1023
    const int b    = bid >> 8;             // batch
    const int rb   = (bid & 255) * ROWS;   // first row of block

    const float*  qb  = query + b * (CC * MM);
    const float4* wsb = ws4 + b * NN;

    // zero slot-max array (1024 words) + counters
    ((unsigned*)aux)[tid]       = 0u;
    ((unsigned*)aux)[tid + 512] = 0u;
    if (tid < ROWS) scnt[tid] = 0u;

    // per-row query scalars (wave-uniform -> SGPRs); constant indices ONLY
    float qx[RPW], qy[RPW], qz[RPW], dm[RPW];
    #pragma unroll
    for (int r = 0; r < RPW; ++r) {
        int m = rb + g * RPW + r;
        qx[r] = rfl(qb[m]);
        qy[r] = rfl(qb[MM + m]);
        qz[r] = rfl(qb[2*MM + m]);
        dm[r] = -__builtin_inff();
    }

    auto stage = [&](int ch, int bi) {
        pts[bi][tid]       = wsb[(ch << 10) + tid];
        pts[bi][512 + tid] = wsb[(ch << 10) + 512 + tid];
    };

    // ---- Pass 1 (SAMPLE = chunks 0..3): per-lane per-row max folded dot ----
    auto comp1 = [&](int bi) {
        #pragma unroll
        for (int t = 0; t < QST; ++t) {
            float4 P = pts[bi][((qt * QST + t) << 6) + lane];
            #pragma unroll
            for (int r = 0; r < RPW; ++r) {
                float dotf = __builtin_fmaf(qz[r], P.z,
                              __builtin_fmaf(qy[r], P.y,
                               __builtin_fmaf(qx[r], P.x, P.w)));
                dm[r] = fmaxf(dm[r], dotf);
            }
        }
    };

    stage(0, 0);
    #pragma unroll 1
    for (int ch = 0; ch < SCH; ch += 2) {
        __syncthreads();                   // buf0 staged (also covers init)
        if (ch + 1 < SCH) stage(ch + 1, 1);
        comp1(0);
        __syncthreads();
        if (ch + 2 < SCH) stage(ch + 2, 0);
        if (ch + 1 < SCH) comp1(1);
    }
    // buffers now hold: buf0 = chunk 2, buf1 = chunk 3

    // ---- selection: slot[s] = max over sample points with n%64==s.
    //      tau = 16th largest of 64 slot-maxes <= sample-dot16 <= full dot16
    //      => valid threshold; >=16 sample points pass (re-found in pass 2
    //      with bit-identical dotf). ----
    #pragma unroll
    for (int r = 0; r < RPW; ++r)
        atomicMax(&aux[g*RPW + r][lane], mapf(dm[r]));
    __syncthreads();

    #pragma unroll
    for (int rr = 0; rr < 2; ++rr) {
        int row = 2*wv + rr;
        unsigned v = aux[row][lane];
        #pragma unroll
        for (int k = 2; k <= 64; k <<= 1) {
            #pragma unroll
            for (int j = k >> 1; j > 0; j >>= 1) {
                unsigned o = __shfl_xor(v, j, 64);
                bool keepmin = (((lane & j) == 0) == ((lane & k) == 0));
                v = keepmin ? (v < o ? v : o) : (v > o ? v : o);
            }
        }
        unsigned tb = __shfl(v, 48, 64);   // 16th largest of 64
        if (lane == 0) rcbits[row] = __float_as_uint(unmapf(tb) - EPSD);
    }
    __syncthreads();                       // rcbits ready; slot-max dead

    float rc[RPW];
    #pragma unroll
    for (int r = 0; r < RPW; ++r)
        rc[r] = rfl(__uint_as_float(rcbits[g*RPW + r]));

    // ---- Pass 2 (ALL chunks; 2,3 resident): collect candidate indices
    //      as ushort into aux (aliased; slot-max dead after barrier) ----
    unsigned short* cbase = (unsigned short*)&aux[0][0];
    auto comp2 = [&](int ch, int bi) {
        #pragma unroll
        for (int t = 0; t < QST; ++t) {
            int st = qt * QST + t;
            float4 P = pts[bi][(st << 6) + lane];
            unsigned n = (unsigned)((ch << 10) + (st << 6) + lane);
            #pragma unroll
            for (int r = 0; r < RPW; ++r) {
                float dotf = __builtin_fmaf(qz[r], P.z,
                              __builtin_fmaf(qy[r], P.y,
                               __builtin_fmaf(qx[r], P.x, P.w)));
                if (dotf >= rc[r]) {                     // rare (~37/row)
                    unsigned pos = atomicAdd(&scnt[g*RPW + r], 1u);
                    if (pos < CANDMAX)
                        cbase[(g*RPW + r) * CANDMAX + pos] = (unsigned short)n;
                }
            }
        }
    };

    comp2(2, 0);
    comp2(3, 1);
    __syncthreads();                       // resident-chunk reads done
    stage(0, 0);
    #pragma unroll 1
    for (int i = 0; i < 6; i += 2) {       // chunk order 0,1,4,5,6,7
        int c0 = (i     < 2) ? i     : i + 2;
        int c1 = (i + 1 < 2) ? i + 1 : i + 3;
        int c2 = (i + 2 < 2) ? i + 2 : i + 4;
        __syncthreads();                   // buf0 staged with c0
        if (i + 1 < 6) stage(c1, 1);
        comp2(c0, 0);
        __syncthreads();
        if (i + 2 < 6) stage(c2, 0);
        if (i + 1 < 6) comp2(c1, 1);
    }
    __syncthreads();

    // ---- Epilogue: wave wv owns rows 2wv, 2wv+1. Exact reference distance
    //      for up to 128 candidates; 2x 64-sort + bitonic merge -> top-16. ----
    #pragma unroll
    for (int rr = 0; rr < 2; ++rr) {
        int row = 2*wv + rr;
        int m   = rb + row;
        float ex = rfl(qb[m]);
        float ey = rfl(qb[MM + m]);
        float ez = rfl(qb[2*MM + m]);
        float eq2 = rfl(__fadd_rn(__fadd_rn(__fmul_rn(ex,ex), __fmul_rn(ey,ey)),
                                  __fmul_rn(ez,ez)));
        unsigned c = scnt[row]; if (c > CANDMAX) c = CANDMAX;  // >=16 guaranteed
        const unsigned short* c16 = cbase + row * CANDMAX;

        unsigned kb0 = ~0u, id0 = ~0u, kb1 = ~0u, id1 = ~0u;
        if (lane < (int)c) {
            id0 = c16[lane];
            float4 P = wsb[id0];
            float p2  = __fmul_rn(-2.0f, P.w);   // exact recovery of ref p2
            float dot = __builtin_fmaf(ez, P.z,
                         __builtin_fmaf(ey, P.y, __fmul_rn(ex, P.x)));
            kb0 = mapf(__fsub_rn(__fadd_rn(eq2, p2), __fmul_rn(2.0f, dot)));
        }
        if (64 + lane < (int)c) {
            id1 = c16[64 + lane];
            float4 P = wsb[id1];
            float p2  = __fmul_rn(-2.0f, P.w);
            float dot = __builtin_fmaf(ez, P.z,
                         __builtin_fmaf(ey, P.y, __fmul_rn(ex, P.x)));
            kb1 = mapf(__fsub_rn(__fadd_rn(eq2, p2), __fmul_rn(2.0f, dot)));
        }

        auto bsort = [&](unsigned& kb, unsigned& id) {
            #pragma unroll
            for (int k = 2; k <= 64; k <<= 1) {
                #pragma unroll
                for (int j = k >> 1; j > 0; j >>= 1) {
                    unsigned ok = __shfl_xor(kb, j, 64);
                    unsigned oi = __shfl_xor(id, j, 64);
                    bool takeMin  = (((lane & j) == 0) == ((lane & k) == 0));
                    bool selfLess = (kb < ok) || (kb == ok && id < oi);
                    if (selfLess != takeMin) { kb = ok; id = oi; }
                }
            }
        };
        bsort(kb0, id0);
        bsort(kb1, id1);
        // merge step: min(A[lane], B[63-lane]) = 64 smallest, bitonic
        unsigned rk = __shfl(kb1, 63 - lane, 64);
        unsigned ri = __shfl(id1, 63 - lane, 64);
        bool pLess = (rk < kb0) || (rk == kb0 && ri < id0);
        if (pLess) { kb0 = rk; id0 = ri; }
        #pragma unroll
        for (int j = 32; j > 0; j >>= 1) {   // ascending bitonic merge
            unsigned ok = __shfl_xor(kb0, j, 64);
            unsigned oi = __shfl_xor(id0, j, 64);
            bool selfLess = (kb0 < ok) || (kb0 == ok && id0 < oi);
            bool takeMin  = ((lane & j) == 0);
            if (selfLess != takeMin) { kb0 = ok; id0 = oi; }
        }

        if (lane < KK) {
            int oi = (int)id0;
            float4 P = wsb[oi];              // x,y,z bit-exact copies of points
            out[NP_OFF + (b * MM + m) * KK + lane] = (float)oi;
            out[((b * CC + 0) * MM + m) * KK + lane] = P.x;
            out[((b * CC + 1) * MM + m) * KK + lane] = P.y;
            out[((b * CC + 2) * MM + m) * KK + lane] = P.z;
        }
    }
}

extern "C" void kernel_launch(void* const* d_in, const int* in_sizes, int n_in,
                              void* d_out, int out_size, void* d_ws, size_t ws_size,
                              hipStream_t stream) {
    // d_in[0] = k (scalar, =16), d_in[1] = query f32 [4,3,4096],
    // d_in[2] = points f32 [4,3,8192]
    const float* query  = (const float*)d_in[1];
    const float* points = (const float*)d_in[2];
    float4* ws4 = (float4*)d_ws;           // 4*8192*16 B = 512 KB
    float* out = (float*)d_out;
    prep_kernel<<<dim3((BQ*NN)/256), dim3(256), 0, stream>>>(points, ws4);
    dim3 grid(BQ * (MM / ROWS));           // 1024 blocks = 4/CU, 8 waves each
    dim3 block(BLOCK);
    knn_kernel<<<grid, block, 0, stream>>>(query, ws4, out);
}